// Round 1
// baseline (423.222 us; speedup 1.0000x reference)
//
#include <hip/hip_runtime.h>
#include <math.h>
#include <stdint.h>

#define LN_EPS 1e-5f

__device__ __forceinline__ float waveSum64(float v) {
#pragma unroll
  for (int off = 32; off >= 1; off >>= 1) v += __shfl_xor(v, off, 64);
  return v;
}

// ---- CSR build ----------------------------------------------------------

__global__ void k_count(const int* __restrict__ dstA, int E, int* __restrict__ counts) {
  int e = blockIdx.x * blockDim.x + threadIdx.x;
  if (e < E) atomicAdd(&counts[dstA[e]], 1);
}

__global__ void k_scan1(const int* __restrict__ counts, int N,
                        int* __restrict__ offsets, int* __restrict__ blockSums) {
  __shared__ int sh[256];
  int t = threadIdx.x;
  int i = blockIdx.x * 256 + t;
  int v = (i < N) ? counts[i] : 0;
  sh[t] = v;
  __syncthreads();
  for (int off = 1; off < 256; off <<= 1) {
    int x = (t >= off) ? sh[t - off] : 0;
    __syncthreads();
    sh[t] += x;
    __syncthreads();
  }
  if (i < N) offsets[i] = sh[t] - v;  // exclusive
  if (t == 255) blockSums[blockIdx.x] = sh[t];
}

__global__ void k_scan2(int* __restrict__ blockSums, int NB) {
  __shared__ int sh[256];
  int t = threadIdx.x;
  int v = (t < NB) ? blockSums[t] : 0;
  sh[t] = v;
  __syncthreads();
  for (int off = 1; off < 256; off <<= 1) {
    int x = (t >= off) ? sh[t - off] : 0;
    __syncthreads();
    sh[t] += x;
    __syncthreads();
  }
  if (t < NB) blockSums[t] = sh[t] - v;  // exclusive
}

__global__ void k_scan3(int* __restrict__ offsets, int* __restrict__ cursor,
                        const int* __restrict__ blockSums, int N, int E) {
  int i = blockIdx.x * 256 + threadIdx.x;
  if (i < N) {
    int o = offsets[i] + blockSums[blockIdx.x];
    offsets[i] = o;
    cursor[i] = o;
  }
  if (i == 0) offsets[N] = E;
}

__global__ void k_scatter(const int* __restrict__ srcA, const int* __restrict__ dstA, int E,
                          int* __restrict__ cursor, int* __restrict__ csr_src) {
  int e = blockIdx.x * blockDim.x + threadIdx.x;
  if (e < E) {
    int pos = atomicAdd(&cursor[dstA[e]], 1);
    csr_src[pos] = srcA[e];
  }
}

// ---- Layer 1 ------------------------------------------------------------

// k1,v1 = x @ Wk1, x @ Wv1   (x: [N,13], W: [13,64])
__global__ void k_proj1(const float* __restrict__ x, const float* __restrict__ Wk,
                        const float* __restrict__ Wv, int N,
                        float* __restrict__ kb, float* __restrict__ vb) {
  int t = blockIdx.x * blockDim.x + threadIdx.x;
  int n = t >> 6, j = t & 63;
  if (n >= N) return;
  const float* xr = x + n * 13;
  float ak = 0.f, av = 0.f;
#pragma unroll
  for (int i = 0; i < 13; ++i) {
    float xv = xr[i];
    ak = fmaf(xv, Wk[i * 64 + j], ak);
    av = fmaf(xv, Wv[i * 64 + j], av);
  }
  kb[t] = ak;
  vb[t] = av;
}

// One wave per node: inline q = x@Wq, res = x@Wr, segment softmax over
// in-edges (CSR), aggregate v, +res, LayerNorm -> H1.
__global__ void __launch_bounds__(256) k_gat1(
    const float* __restrict__ x, const float* __restrict__ Wq, const float* __restrict__ Wr,
    const float* __restrict__ kb, const float* __restrict__ vb,
    const int* __restrict__ offsets, const int* __restrict__ csr_src,
    const float* __restrict__ g, const float* __restrict__ b,
    int N, float* __restrict__ H1) {
  __shared__ float sWq[13 * 64];
  __shared__ float sWr[13 * 64];
  for (int i = threadIdx.x; i < 13 * 64; i += 256) { sWq[i] = Wq[i]; sWr[i] = Wr[i]; }
  __syncthreads();
  int wid = threadIdx.x >> 6, lane = threadIdx.x & 63;
  int n = blockIdx.x * 4 + wid;
  if (n >= N) return;
  const float* xr = x + n * 13;
  float q = 0.f, r = 0.f;
#pragma unroll
  for (int i = 0; i < 13; ++i) {
    float xv = xr[i];
    q = fmaf(xv, sWq[i * 64 + lane], q);
    r = fmaf(xv, sWr[i * 64 + lane], r);
  }
  q *= 0.25f;  // 1/sqrt(dh), folded into q
  int e0 = offsets[n], e1 = offsets[n + 1];
  int deg = e1 - e0;
  float denom = 0.f, acc = 0.f;
  for (int base = 0; base < deg; base += 64) {
    int idx = base + lane;
    int sv = (idx < deg) ? csr_src[e0 + idx] : 0;  // batch 64 srcs into lanes
    int cnt = min(64, deg - base);
    for (int tt = 0; tt < cnt; ++tt) {
      int s = __shfl(sv, tt, 64);
      float kv = kb[s * 64 + lane];
      float p = q * kv;  // per-head dot over 16-lane group
      p += __shfl_xor(p, 8, 64);
      p += __shfl_xor(p, 4, 64);
      p += __shfl_xor(p, 2, 64);
      p += __shfl_xor(p, 1, 64);
      float ex = __expf(p);
      denom += ex;
      acc = fmaf(ex, vb[s * 64 + lane], acc);
    }
  }
  float out = acc / (denom + 1e-16f);  // deg==0 -> 0/1e-16 = 0, matches ref
  float h = out + r;
  float mu = waveSum64(h) * 0.015625f;
  float d = h - mu;
  float var = waveSum64(d * d) * 0.015625f;
  H1[n * 64 + lane] = fmaf(g[lane], d * rsqrtf(var + LN_EPS), b[lane]);
}

// ---- Layer 2 ------------------------------------------------------------

// k2,v2 = H1 @ Wk2, H1 @ Wv2  (W: [64,64] staged in LDS)
__global__ void __launch_bounds__(256) k_proj2(
    const float* __restrict__ H1, const float* __restrict__ Wk, const float* __restrict__ Wv,
    int N, float* __restrict__ kb, float* __restrict__ vb) {
  __shared__ float sWk[64 * 64];
  __shared__ float sWv[64 * 64];
  for (int i = threadIdx.x; i < 64 * 64; i += 256) { sWk[i] = Wk[i]; sWv[i] = Wv[i]; }
  __syncthreads();
  int t = blockIdx.x * 256 + threadIdx.x;
  int n = t >> 6, j = t & 63;
  if (n >= N) return;
  const float* hr = H1 + n * 64;
  float ak = 0.f, av = 0.f;
#pragma unroll 8
  for (int i = 0; i < 64; ++i) {
    float xv = hr[i];
    ak = fmaf(xv, sWk[i * 64 + j], ak);
    av = fmaf(xv, sWv[i * 64 + j], av);
  }
  kb[t] = ak;
  vb[t] = av;
}

__global__ void __launch_bounds__(256) k_gat2(
    const float* __restrict__ H1, const float* __restrict__ Wq,
    const float* __restrict__ kb, const float* __restrict__ vb,
    const int* __restrict__ offsets, const int* __restrict__ csr_src,
    const float* __restrict__ g, const float* __restrict__ b,
    int N, float* __restrict__ H2) {
  __shared__ float sWq[64 * 64];
  for (int i = threadIdx.x; i < 64 * 64; i += 256) sWq[i] = Wq[i];
  __syncthreads();
  int wid = threadIdx.x >> 6, lane = threadIdx.x & 63;
  int n = blockIdx.x * 4 + wid;
  if (n >= N) return;
  const float* hr = H1 + n * 64;
  float q = 0.f;
#pragma unroll 8
  for (int i = 0; i < 64; ++i) q = fmaf(hr[i], sWq[i * 64 + lane], q);
  q *= 0.25f;
  float r = hr[lane];  // identity residual
  int e0 = offsets[n], e1 = offsets[n + 1];
  int deg = e1 - e0;
  float denom = 0.f, acc = 0.f;
  for (int base = 0; base < deg; base += 64) {
    int idx = base + lane;
    int sv = (idx < deg) ? csr_src[e0 + idx] : 0;
    int cnt = min(64, deg - base);
    for (int tt = 0; tt < cnt; ++tt) {
      int s = __shfl(sv, tt, 64);
      float kv = kb[s * 64 + lane];
      float p = q * kv;
      p += __shfl_xor(p, 8, 64);
      p += __shfl_xor(p, 4, 64);
      p += __shfl_xor(p, 2, 64);
      p += __shfl_xor(p, 1, 64);
      float ex = __expf(p);
      denom += ex;
      acc = fmaf(ex, vb[s * 64 + lane], acc);
    }
  }
  float out = acc / (denom + 1e-16f);
  float h = out + r;
  float mu = waveSum64(h) * 0.015625f;
  float d = h - mu;
  float var = waveSum64(d * d) * 0.015625f;
  H2[n * 64 + lane] = fmaf(g[lane], d * rsqrtf(var + LN_EPS), b[lane]);
}

// ---- Pooling ------------------------------------------------------------

__global__ void k_pool(const float* __restrict__ H2, const int* __restrict__ ptr,
                       float* __restrict__ Q) {
  __shared__ float sh[4 * 64];
  int gI = blockIdx.x;
  int start = ptr[gI], end = ptr[gI + 1];
  int wid = threadIdx.x >> 6, lane = threadIdx.x & 63;
  float acc = 0.f;
  for (int n = start + wid; n < end; n += 4) acc += H2[n * 64 + lane];
  sh[wid * 64 + lane] = acc;
  __syncthreads();
  if (wid == 0) {
    float s = sh[lane] + sh[64 + lane] + sh[128 + lane] + sh[192 + lane];
    Q[gI * 64 + lane] = s / (float)(end - start);
  }
}

// ---- Launch -------------------------------------------------------------

extern "C" void kernel_launch(void* const* d_in, const int* in_sizes, int n_in,
                              void* d_out, int out_size, void* d_ws, size_t ws_size,
                              hipStream_t stream) {
  const float* nodes = (const float*)d_in[0];
  const int* eidx    = (const int*)d_in[1];
  const int* bptr    = (const int*)d_in[2];
  const float* Wq1 = (const float*)d_in[3];
  const float* Wk1 = (const float*)d_in[4];
  const float* Wv1 = (const float*)d_in[5];
  const float* Wr1 = (const float*)d_in[6];
  const float* g1  = (const float*)d_in[7];
  const float* b1  = (const float*)d_in[8];
  const float* Wq2 = (const float*)d_in[9];
  const float* Wk2 = (const float*)d_in[10];
  const float* Wv2 = (const float*)d_in[11];
  const float* g2  = (const float*)d_in[12];
  const float* b2  = (const float*)d_in[13];

  const int N = in_sizes[0] / 13;
  const int E = in_sizes[1] / 2;
  const int B = in_sizes[2] - 1;
  const int* srcA = eidx;
  const int* dstA = eidx + E;

  // workspace carve (ints first, then 256B-aligned float buffers)
  char* w = (char*)d_ws;
  int* counts    = (int*)w; w += (size_t)N * 4;          // reused as scatter cursor
  int* offsets   = (int*)w; w += (size_t)(N + 1) * 4;
  int* blockSums = (int*)w; w += 256 * 4;
  int* csr_src   = (int*)w; w += (size_t)E * 4;
  w = (char*)(((uintptr_t)w + 255) & ~(uintptr_t)255);
  float* kb = (float*)w; w += (size_t)N * 64 * 4;
  float* vb = (float*)w; w += (size_t)N * 64 * 4;
  float* H1 = (float*)w; w += (size_t)N * 64 * 4;

  float* H2 = (float*)d_out;
  float* Q  = H2 + (size_t)N * 64;

  const int NB = (N + 255) / 256;      // 196 for N=50000 (fits single-block scan2)
  const int EB = (E + 255) / 256;
  const int GB = (N + 3) / 4;          // one wave per node, 4 waves/block

  hipMemsetAsync(counts, 0, (size_t)N * 4, stream);
  k_count<<<EB, 256, 0, stream>>>(dstA, E, counts);
  k_scan1<<<NB, 256, 0, stream>>>(counts, N, offsets, blockSums);
  k_scan2<<<1, 256, 0, stream>>>(blockSums, NB);
  k_scan3<<<NB, 256, 0, stream>>>(offsets, counts, blockSums, N, E);
  k_scatter<<<EB, 256, 0, stream>>>(srcA, dstA, E, counts, csr_src);

  k_proj1<<<(N * 64 + 255) / 256, 256, 0, stream>>>(nodes, Wk1, Wv1, N, kb, vb);
  k_gat1<<<GB, 256, 0, stream>>>(nodes, Wq1, Wr1, kb, vb, offsets, csr_src, g1, b1, N, H1);
  k_proj2<<<(N * 64 + 255) / 256, 256, 0, stream>>>(H1, Wk2, Wv2, N, kb, vb);
  k_gat2<<<GB, 256, 0, stream>>>(H1, Wq2, kb, vb, offsets, csr_src, g2, b2, N, H2);
  k_pool<<<B, 256, 0, stream>>>(H2, bptr, Q);
}

// Round 2
// 381.964 us; speedup vs baseline: 1.1080x; 1.1080x over previous
//
#include <hip/hip_runtime.h>
#include <math.h>
#include <stdint.h>

#define LN_EPS 1e-5f

__device__ __forceinline__ float waveSum64(float v) {
#pragma unroll
  for (int off = 32; off >= 1; off >>= 1) v += __shfl_xor(v, off, 64);
  return v;
}

// ---- CSR build ----------------------------------------------------------

__global__ void k_count(const int* __restrict__ dstA, int E, int* __restrict__ counts) {
  int e = blockIdx.x * blockDim.x + threadIdx.x;
  if (e < E) atomicAdd(&counts[dstA[e]], 1);
}

__global__ void k_scan1(const int* __restrict__ counts, int N,
                        int* __restrict__ offsets, int* __restrict__ blockSums) {
  __shared__ int sh[256];
  int t = threadIdx.x;
  int i = blockIdx.x * 256 + t;
  int v = (i < N) ? counts[i] : 0;
  sh[t] = v;
  __syncthreads();
  for (int off = 1; off < 256; off <<= 1) {
    int x = (t >= off) ? sh[t - off] : 0;
    __syncthreads();
    sh[t] += x;
    __syncthreads();
  }
  if (i < N) offsets[i] = sh[t] - v;  // exclusive
  if (t == 255) blockSums[blockIdx.x] = sh[t];
}

__global__ void k_scan2(int* __restrict__ blockSums, int NB) {
  __shared__ int sh[256];
  int t = threadIdx.x;
  int v = (t < NB) ? blockSums[t] : 0;
  sh[t] = v;
  __syncthreads();
  for (int off = 1; off < 256; off <<= 1) {
    int x = (t >= off) ? sh[t - off] : 0;
    __syncthreads();
    sh[t] += x;
    __syncthreads();
  }
  if (t < NB) blockSums[t] = sh[t] - v;  // exclusive
}

__global__ void k_scan3(int* __restrict__ offsets, int* __restrict__ cursor,
                        const int* __restrict__ blockSums, int N, int E) {
  int i = blockIdx.x * 256 + threadIdx.x;
  if (i < N) {
    int o = offsets[i] + blockSums[blockIdx.x];
    offsets[i] = o;
    cursor[i] = o;
  }
  if (i == 0) offsets[N] = E;
}

__global__ void k_scatter(const int* __restrict__ srcA, const int* __restrict__ dstA, int E,
                          int* __restrict__ cursor, int* __restrict__ csr_src) {
  int e = blockIdx.x * blockDim.x + threadIdx.x;
  if (e < E) {
    int pos = atomicAdd(&cursor[dstA[e]], 1);
    csr_src[pos] = srcA[e];
  }
}

// ---- Projections: write interleaved {k,v} per channel -------------------

// kv[n][ch] = {x@Wk, x@Wv}  (x: [N,13])
__global__ void k_proj1(const float* __restrict__ x, const float* __restrict__ Wk,
                        const float* __restrict__ Wv, int N,
                        float2* __restrict__ kv) {
  int t = blockIdx.x * blockDim.x + threadIdx.x;
  int n = t >> 6, j = t & 63;
  if (n >= N) return;
  const float* xr = x + n * 13;
  float ak = 0.f, av = 0.f;
#pragma unroll
  for (int i = 0; i < 13; ++i) {
    float xv = xr[i];
    ak = fmaf(xv, Wk[i * 64 + j], ak);
    av = fmaf(xv, Wv[i * 64 + j], av);
  }
  kv[t] = make_float2(ak, av);
}

// kv[n][ch] = {H1@Wk2, H1@Wv2}  (W: [64,64] staged in LDS)
__global__ void __launch_bounds__(256) k_proj2(
    const float* __restrict__ H1, const float* __restrict__ Wk, const float* __restrict__ Wv,
    int N, float2* __restrict__ kv) {
  __shared__ float sWk[64 * 64];
  __shared__ float sWv[64 * 64];
  for (int i = threadIdx.x; i < 64 * 64; i += 256) { sWk[i] = Wk[i]; sWv[i] = Wv[i]; }
  __syncthreads();
  int t = blockIdx.x * 256 + threadIdx.x;
  int n = t >> 6, j = t & 63;
  if (n >= N) return;
  const float* hr = H1 + n * 64;
  float ak = 0.f, av = 0.f;
#pragma unroll 8
  for (int i = 0; i < 64; ++i) {
    float xv = hr[i];
    ak = fmaf(xv, sWk[i * 64 + j], ak);
    av = fmaf(xv, sWv[i * 64 + j], av);
  }
  kv[t] = make_float2(ak, av);
}

// ---- GAT aggregation core (edge loop, unrolled x4) ----------------------

__device__ __forceinline__ void edge_loop(const float2* __restrict__ kv,
                                          const int* __restrict__ csr_src,
                                          int e0, int deg, int lane, float q,
                                          float& denom, float& acc) {
  for (int base = 0; base < deg; base += 64) {
    int idx = base + lane;
    int sv = (idx < deg) ? csr_src[e0 + idx] : 0;  // batch 64 srcs into lanes
    int cnt = min(64, deg - base);
    int tt = 0;
    for (; tt + 4 <= cnt; tt += 4) {
      int s0 = __shfl(sv, tt, 64);
      int s1 = __shfl(sv, tt + 1, 64);
      int s2 = __shfl(sv, tt + 2, 64);
      int s3 = __shfl(sv, tt + 3, 64);
      float2 a0 = kv[(size_t)s0 * 64 + lane];
      float2 a1 = kv[(size_t)s1 * 64 + lane];
      float2 a2 = kv[(size_t)s2 * 64 + lane];
      float2 a3 = kv[(size_t)s3 * 64 + lane];
      float p0 = q * a0.x, p1 = q * a1.x, p2 = q * a2.x, p3 = q * a3.x;
#pragma unroll
      for (int off = 8; off >= 1; off >>= 1) {
        p0 += __shfl_xor(p0, off, 64);
        p1 += __shfl_xor(p1, off, 64);
        p2 += __shfl_xor(p2, off, 64);
        p3 += __shfl_xor(p3, off, 64);
      }
      float x0 = __expf(p0), x1 = __expf(p1), x2 = __expf(p2), x3 = __expf(p3);
      denom += (x0 + x1) + (x2 + x3);
      acc = fmaf(x0, a0.y, acc);
      acc = fmaf(x1, a1.y, acc);
      acc = fmaf(x2, a2.y, acc);
      acc = fmaf(x3, a3.y, acc);
    }
    for (; tt < cnt; ++tt) {
      int s = __shfl(sv, tt, 64);
      float2 a = kv[(size_t)s * 64 + lane];
      float p = q * a.x;
#pragma unroll
      for (int off = 8; off >= 1; off >>= 1) p += __shfl_xor(p, off, 64);
      float ex = __expf(p);
      denom += ex;
      acc = fmaf(ex, a.y, acc);
    }
  }
}

// ---- Layer 1: one wave per node -----------------------------------------

__global__ void __launch_bounds__(512) k_gat1(
    const float* __restrict__ x, const float* __restrict__ Wq, const float* __restrict__ Wr,
    const float2* __restrict__ kv,
    const int* __restrict__ offsets, const int* __restrict__ csr_src,
    const float* __restrict__ g, const float* __restrict__ b,
    int N, float* __restrict__ H1) {
  __shared__ float sWq[13 * 64];
  __shared__ float sWr[13 * 64];
  for (int i = threadIdx.x; i < 13 * 64; i += 512) { sWq[i] = Wq[i]; sWr[i] = Wr[i]; }
  __syncthreads();
  int wid = threadIdx.x >> 6, lane = threadIdx.x & 63;
  int n = blockIdx.x * 8 + wid;
  if (n >= N) return;
  const float* xr = x + n * 13;
  float q = 0.f, r = 0.f;
#pragma unroll
  for (int i = 0; i < 13; ++i) {
    float xv = xr[i];
    q = fmaf(xv, sWq[i * 64 + lane], q);
    r = fmaf(xv, sWr[i * 64 + lane], r);
  }
  q *= 0.25f;  // 1/sqrt(dh) folded into q
  int e0 = offsets[n];
  int deg = offsets[n + 1] - e0;
  float denom = 0.f, acc = 0.f;
  edge_loop(kv, csr_src, e0, deg, lane, q, denom, acc);
  float out = acc / (denom + 1e-16f);  // deg==0 -> 0, matches ref
  float h = out + r;
  float mu = waveSum64(h) * 0.015625f;
  float d = h - mu;
  float var = waveSum64(d * d) * 0.015625f;
  H1[(size_t)n * 64 + lane] = fmaf(g[lane], d * rsqrtf(var + LN_EPS), b[lane]);
}

// ---- Layer 2 ------------------------------------------------------------

__global__ void __launch_bounds__(512) k_gat2(
    const float* __restrict__ H1, const float* __restrict__ Wq,
    const float2* __restrict__ kv,
    const int* __restrict__ offsets, const int* __restrict__ csr_src,
    const float* __restrict__ g, const float* __restrict__ b,
    int N, float* __restrict__ H2) {
  __shared__ float sWq[64 * 64];
  for (int i = threadIdx.x; i < 64 * 64; i += 512) sWq[i] = Wq[i];
  __syncthreads();
  int wid = threadIdx.x >> 6, lane = threadIdx.x & 63;
  int n = blockIdx.x * 8 + wid;
  if (n >= N) return;
  const float* hr = H1 + (size_t)n * 64;
  float q = 0.f;
#pragma unroll 8
  for (int i = 0; i < 64; ++i) q = fmaf(hr[i], sWq[i * 64 + lane], q);
  q *= 0.25f;
  float r = hr[lane];  // identity residual
  int e0 = offsets[n];
  int deg = offsets[n + 1] - e0;
  float denom = 0.f, acc = 0.f;
  edge_loop(kv, csr_src, e0, deg, lane, q, denom, acc);
  float out = acc / (denom + 1e-16f);
  float h = out + r;
  float mu = waveSum64(h) * 0.015625f;
  float d = h - mu;
  float var = waveSum64(d * d) * 0.015625f;
  H2[(size_t)n * 64 + lane] = fmaf(g[lane], d * rsqrtf(var + LN_EPS), b[lane]);
}

// ---- Pooling ------------------------------------------------------------

__global__ void k_pool(const float* __restrict__ H2, const int* __restrict__ ptr,
                       float* __restrict__ Q) {
  __shared__ float sh[4 * 64];
  int gI = blockIdx.x;
  int start = ptr[gI], end = ptr[gI + 1];
  int wid = threadIdx.x >> 6, lane = threadIdx.x & 63;
  float acc = 0.f;
  for (int n = start + wid; n < end; n += 4) acc += H2[(size_t)n * 64 + lane];
  sh[wid * 64 + lane] = acc;
  __syncthreads();
  if (wid == 0) {
    float s = sh[lane] + sh[64 + lane] + sh[128 + lane] + sh[192 + lane];
    Q[gI * 64 + lane] = s / (float)(end - start);
  }
}

// ---- Launch -------------------------------------------------------------

extern "C" void kernel_launch(void* const* d_in, const int* in_sizes, int n_in,
                              void* d_out, int out_size, void* d_ws, size_t ws_size,
                              hipStream_t stream) {
  const float* nodes = (const float*)d_in[0];
  const int* eidx    = (const int*)d_in[1];
  const int* bptr    = (const int*)d_in[2];
  const float* Wq1 = (const float*)d_in[3];
  const float* Wk1 = (const float*)d_in[4];
  const float* Wv1 = (const float*)d_in[5];
  const float* Wr1 = (const float*)d_in[6];
  const float* g1  = (const float*)d_in[7];
  const float* b1  = (const float*)d_in[8];
  const float* Wq2 = (const float*)d_in[9];
  const float* Wk2 = (const float*)d_in[10];
  const float* Wv2 = (const float*)d_in[11];
  const float* g2  = (const float*)d_in[12];
  const float* b2  = (const float*)d_in[13];

  const int N = in_sizes[0] / 13;
  const int E = in_sizes[1] / 2;
  const int B = in_sizes[2] - 1;
  const int* srcA = eidx;
  const int* dstA = eidx + E;

  // workspace carve (ints first, then 256B-aligned float buffers)
  char* w = (char*)d_ws;
  int* counts    = (int*)w; w += (size_t)N * 4;          // reused as scatter cursor
  int* offsets   = (int*)w; w += (size_t)(N + 1) * 4;
  int* blockSums = (int*)w; w += 256 * 4;
  int* csr_src   = (int*)w; w += (size_t)E * 4;
  w = (char*)(((uintptr_t)w + 255) & ~(uintptr_t)255);
  float2* kvb = (float2*)w; w += (size_t)N * 64 * 8;  // interleaved {k,v}
  float*  H1  = (float*)w;  w += (size_t)N * 64 * 4;

  float* H2 = (float*)d_out;
  float* Q  = H2 + (size_t)N * 64;

  const int NB = (N + 255) / 256;      // 196 blocks -> single-block scan2 ok
  const int EB = (E + 255) / 256;
  const int GB = (N + 7) / 8;          // one wave per node, 8 waves/block

  hipMemsetAsync(counts, 0, (size_t)N * 4, stream);
  k_count<<<EB, 256, 0, stream>>>(dstA, E, counts);
  k_scan1<<<NB, 256, 0, stream>>>(counts, N, offsets, blockSums);
  k_scan2<<<1, 256, 0, stream>>>(blockSums, NB);
  k_scan3<<<NB, 256, 0, stream>>>(offsets, counts, blockSums, N, E);
  k_scatter<<<EB, 256, 0, stream>>>(srcA, dstA, E, counts, csr_src);

  k_proj1<<<(N * 64 + 255) / 256, 256, 0, stream>>>(nodes, Wk1, Wv1, N, kvb);
  k_gat1<<<GB, 512, 0, stream>>>(nodes, Wq1, Wr1, kvb, offsets, csr_src, g1, b1, N, H1);
  k_proj2<<<(N * 64 + 255) / 256, 256, 0, stream>>>(H1, Wk2, Wv2, N, kvb);
  k_gat2<<<GB, 512, 0, stream>>>(H1, Wq2, kvb, offsets, csr_src, g2, b2, N, H2);
  k_pool<<<B, 256, 0, stream>>>(H2, bptr, Q);
}

// Round 3
// 338.277 us; speedup vs baseline: 1.2511x; 1.1291x over previous
//
#include <hip/hip_runtime.h>
#include <math.h>
#include <stdint.h>

#define LN_EPS 1e-5f

// ---- CSR build ----------------------------------------------------------

__global__ void k_count(const int* __restrict__ dstA, int E, int* __restrict__ counts) {
  int e = blockIdx.x * blockDim.x + threadIdx.x;
  if (e < E) atomicAdd(&counts[dstA[e]], 1);
}

__global__ void k_scan1(const int* __restrict__ counts, int N,
                        int* __restrict__ offsets, int* __restrict__ blockSums) {
  __shared__ int sh[256];
  int t = threadIdx.x;
  int i = blockIdx.x * 256 + t;
  int v = (i < N) ? counts[i] : 0;
  sh[t] = v;
  __syncthreads();
  for (int off = 1; off < 256; off <<= 1) {
    int x = (t >= off) ? sh[t - off] : 0;
    __syncthreads();
    sh[t] += x;
    __syncthreads();
  }
  if (i < N) offsets[i] = sh[t] - v;  // exclusive
  if (t == 255) blockSums[blockIdx.x] = sh[t];
}

__global__ void k_scan2(int* __restrict__ blockSums, int NB) {
  __shared__ int sh[256];
  int t = threadIdx.x;
  int v = (t < NB) ? blockSums[t] : 0;
  sh[t] = v;
  __syncthreads();
  for (int off = 1; off < 256; off <<= 1) {
    int x = (t >= off) ? sh[t - off] : 0;
    __syncthreads();
    sh[t] += x;
    __syncthreads();
  }
  if (t < NB) blockSums[t] = sh[t] - v;  // exclusive
}

__global__ void k_scan3(int* __restrict__ offsets, int* __restrict__ cursor,
                        const int* __restrict__ blockSums, int N, int E) {
  int i = blockIdx.x * 256 + threadIdx.x;
  if (i < N) {
    int o = offsets[i] + blockSums[blockIdx.x];
    offsets[i] = o;
    cursor[i] = o;
  }
  if (i == 0) offsets[N] = E;
}

__global__ void k_scatter(const int* __restrict__ srcA, const int* __restrict__ dstA, int E,
                          int* __restrict__ cursor, int* __restrict__ csr_src) {
  int e = blockIdx.x * blockDim.x + threadIdx.x;
  if (e < E) {
    int pos = atomicAdd(&cursor[dstA[e]], 1);
    csr_src[pos] = srcA[e];
  }
}

// ---- Projections: write interleaved {k,v} per channel -------------------

__global__ void k_proj1(const float* __restrict__ x, const float* __restrict__ Wk,
                        const float* __restrict__ Wv, int N,
                        float2* __restrict__ kv) {
  int t = blockIdx.x * blockDim.x + threadIdx.x;
  int n = t >> 6, j = t & 63;
  if (n >= N) return;
  const float* xr = x + n * 13;
  float ak = 0.f, av = 0.f;
#pragma unroll
  for (int i = 0; i < 13; ++i) {
    float xv = xr[i];
    ak = fmaf(xv, Wk[i * 64 + j], ak);
    av = fmaf(xv, Wv[i * 64 + j], av);
  }
  kv[t] = make_float2(ak, av);
}

// grid-strided: stage W once per block, loop over many nodes
__global__ void __launch_bounds__(256) k_proj2(
    const float* __restrict__ H1, const float* __restrict__ Wk, const float* __restrict__ Wv,
    int N, float2* __restrict__ kv) {
  __shared__ float sWk[64 * 64];
  __shared__ float sWv[64 * 64];
  for (int i = threadIdx.x; i < 64 * 64; i += 256) { sWk[i] = Wk[i]; sWv[i] = Wv[i]; }
  __syncthreads();
  int total = N * 64;
  int stride = gridDim.x * 256;
  for (int t = blockIdx.x * 256 + threadIdx.x; t < total; t += stride) {
    int n = t >> 6, j = t & 63;
    const float* hr = H1 + (size_t)n * 64;
    float ak = 0.f, av = 0.f;
#pragma unroll 8
    for (int i = 0; i < 64; ++i) {
      float xv = hr[i];
      ak = fmaf(xv, sWk[i * 64 + j], ak);
      av = fmaf(xv, sWv[i * 64 + j], av);
    }
    kv[t] = make_float2(ak, av);
  }
}

// ---- GAT edge loop: 16 lanes per edge, 4 channels per lane, 8 edges in flight

__device__ __forceinline__ void edge_loop4(const float4* __restrict__ kvf4,
                                           const int* __restrict__ csr_src,
                                           int e0, int deg, int lane, float4 q4,
                                           float& denom, float4& acc) {
  int grp = lane >> 4;          // which edge slot this lane serves
  int hp = (lane & 15) * 2;     // float4 pair index within kv row (32 float4s/row)
  for (int base = 0; base < deg; base += 8) {
    int i0 = base + grp, i1 = base + 4 + grp;
    bool v0 = i0 < deg, v1 = i1 < deg;
    int s0 = v0 ? csr_src[e0 + i0] : 0;
    int s1 = v1 ? csr_src[e0 + i1] : 0;
    float4 a0 = kvf4[(size_t)s0 * 32 + hp];      // {k0,v0,k1,v1}
    float4 b0 = kvf4[(size_t)s0 * 32 + hp + 1];  // {k2,v2,k3,v3}
    float4 a1 = kvf4[(size_t)s1 * 32 + hp];
    float4 b1 = kvf4[(size_t)s1 * 32 + hp + 1];
    float p0 = q4.x * a0.x + q4.y * a0.z + q4.z * b0.x + q4.w * b0.z;
    float p1 = q4.x * a1.x + q4.y * a1.z + q4.z * b1.x + q4.w * b1.z;
    p0 += __shfl_xor(p0, 1, 64);
    p0 += __shfl_xor(p0, 2, 64);  // head dot over the 4-lane subgroup
    p1 += __shfl_xor(p1, 1, 64);
    p1 += __shfl_xor(p1, 2, 64);
    float x0 = v0 ? __expf(p0) : 0.f;
    float x1 = v1 ? __expf(p1) : 0.f;
    denom += x0 + x1;
    acc.x = fmaf(x0, a0.y, fmaf(x1, a1.y, acc.x));
    acc.y = fmaf(x0, a0.w, fmaf(x1, a1.w, acc.y));
    acc.z = fmaf(x0, b0.y, fmaf(x1, b1.y, acc.z));
    acc.w = fmaf(x0, b0.w, fmaf(x1, b1.w, acc.w));
  }
  // reduce the 4 edge-groups (lanes l, l+16, l+32, l+48 hold same channels)
#pragma unroll
  for (int off = 16; off <= 32; off <<= 1) {
    acc.x += __shfl_xor(acc.x, off, 64);
    acc.y += __shfl_xor(acc.y, off, 64);
    acc.z += __shfl_xor(acc.z, off, 64);
    acc.w += __shfl_xor(acc.w, off, 64);
    denom += __shfl_xor(denom, off, 64);
  }
}

__device__ __forceinline__ void ln_store(float4 out4, float4 r4, int lane,
                                         const float* __restrict__ g,
                                         const float* __restrict__ b,
                                         float* __restrict__ dst) {
  float4 h;
  h.x = out4.x + r4.x; h.y = out4.y + r4.y; h.z = out4.z + r4.z; h.w = out4.w + r4.w;
  float s = (h.x + h.y) + (h.z + h.w);
#pragma unroll
  for (int off = 1; off <= 8; off <<= 1) s += __shfl_xor(s, off, 64);
  float mu = s * 0.015625f;
  float4 d;
  d.x = h.x - mu; d.y = h.y - mu; d.z = h.z - mu; d.w = h.w - mu;
  float v = (d.x * d.x + d.y * d.y) + (d.z * d.z + d.w * d.w);
#pragma unroll
  for (int off = 1; off <= 8; off <<= 1) v += __shfl_xor(v, off, 64);
  float rs = rsqrtf(v * 0.015625f + LN_EPS);
  if (lane < 16) {
    int c = lane * 4;
    float4 g4 = *(const float4*)&g[c];
    float4 b4 = *(const float4*)&b[c];
    float4 o;
    o.x = fmaf(g4.x, d.x * rs, b4.x);
    o.y = fmaf(g4.y, d.y * rs, b4.y);
    o.z = fmaf(g4.z, d.z * rs, b4.z);
    o.w = fmaf(g4.w, d.w * rs, b4.w);
    *(float4*)&dst[c] = o;
  }
}

// ---- Layer 1: one wave per node -----------------------------------------

__global__ void __launch_bounds__(512) k_gat1(
    const float* __restrict__ x, const float* __restrict__ Wq, const float* __restrict__ Wr,
    const float4* __restrict__ kvf4,
    const int* __restrict__ offsets, const int* __restrict__ csr_src,
    const float* __restrict__ g, const float* __restrict__ b,
    int N, float* __restrict__ H1) {
  __shared__ float sWq[13 * 64];
  __shared__ float sWr[13 * 64];
  for (int i = threadIdx.x; i < 13 * 64; i += 512) { sWq[i] = Wq[i]; sWr[i] = Wr[i]; }
  __syncthreads();
  int wid = threadIdx.x >> 6, lane = threadIdx.x & 63;
  int n = blockIdx.x * 8 + wid;
  if (n >= N) return;
  const float* xr = x + (size_t)n * 13;
  float q = 0.f, r = 0.f;
#pragma unroll
  for (int i = 0; i < 13; ++i) {
    float xv = xr[i];
    q = fmaf(xv, sWq[i * 64 + lane], q);
    r = fmaf(xv, sWr[i * 64 + lane], r);
  }
  q *= 0.25f;  // 1/sqrt(dh)
  // transpose lane=channel -> lane holds 4 consecutive channels
  int bl = (lane & 15) * 4;
  float4 q4, r4;
  q4.x = __shfl(q, bl + 0, 64); q4.y = __shfl(q, bl + 1, 64);
  q4.z = __shfl(q, bl + 2, 64); q4.w = __shfl(q, bl + 3, 64);
  r4.x = __shfl(r, bl + 0, 64); r4.y = __shfl(r, bl + 1, 64);
  r4.z = __shfl(r, bl + 2, 64); r4.w = __shfl(r, bl + 3, 64);
  int e0 = offsets[n];
  int deg = offsets[n + 1] - e0;
  float denom = 0.f;
  float4 acc = make_float4(0.f, 0.f, 0.f, 0.f);
  edge_loop4(kvf4, csr_src, e0, deg, lane, q4, denom, acc);
  float inv = 1.0f / (denom + 1e-16f);
  float4 out4 = make_float4(acc.x * inv, acc.y * inv, acc.z * inv, acc.w * inv);
  ln_store(out4, r4, lane, g, b, H1 + (size_t)n * 64);
}

// ---- Layer 2 ------------------------------------------------------------

__global__ void __launch_bounds__(512) k_gat2(
    const float* __restrict__ H1, const float* __restrict__ Wq,
    const float4* __restrict__ kvf4,
    const int* __restrict__ offsets, const int* __restrict__ csr_src,
    const float* __restrict__ g, const float* __restrict__ b,
    int N, float* __restrict__ H2) {
  __shared__ float sWq[64 * 64];
  for (int i = threadIdx.x; i < 64 * 64; i += 512) sWq[i] = Wq[i];
  __syncthreads();
  int wid = threadIdx.x >> 6, lane = threadIdx.x & 63;
  int n = blockIdx.x * 8 + wid;
  if (n >= N) return;
  const float* hr = H1 + (size_t)n * 64;
  float q = 0.f;
#pragma unroll 8
  for (int i = 0; i < 64; ++i) q = fmaf(hr[i], sWq[i * 64 + lane], q);
  q *= 0.25f;
  int bl = (lane & 15) * 4;
  float4 q4;
  q4.x = __shfl(q, bl + 0, 64); q4.y = __shfl(q, bl + 1, 64);
  q4.z = __shfl(q, bl + 2, 64); q4.w = __shfl(q, bl + 3, 64);
  float4 r4 = *(const float4*)&hr[bl];  // identity residual, already 4-ch layout
  int e0 = offsets[n];
  int deg = offsets[n + 1] - e0;
  float denom = 0.f;
  float4 acc = make_float4(0.f, 0.f, 0.f, 0.f);
  edge_loop4(kvf4, csr_src, e0, deg, lane, q4, denom, acc);
  float inv = 1.0f / (denom + 1e-16f);
  float4 out4 = make_float4(acc.x * inv, acc.y * inv, acc.z * inv, acc.w * inv);
  ln_store(out4, r4, lane, g, b, H2 + (size_t)n * 64);
}

// ---- Pooling ------------------------------------------------------------

__global__ void k_pool(const float* __restrict__ H2, const int* __restrict__ ptr,
                       float* __restrict__ Q) {
  __shared__ float sh[4 * 64];
  int gI = blockIdx.x;
  int start = ptr[gI], end = ptr[gI + 1];
  int wid = threadIdx.x >> 6, lane = threadIdx.x & 63;
  float acc = 0.f;
  for (int n = start + wid; n < end; n += 4) acc += H2[(size_t)n * 64 + lane];
  sh[wid * 64 + lane] = acc;
  __syncthreads();
  if (wid == 0) {
    float s = sh[lane] + sh[64 + lane] + sh[128 + lane] + sh[192 + lane];
    Q[gI * 64 + lane] = s / (float)(end - start);
  }
}

// ---- Launch -------------------------------------------------------------

extern "C" void kernel_launch(void* const* d_in, const int* in_sizes, int n_in,
                              void* d_out, int out_size, void* d_ws, size_t ws_size,
                              hipStream_t stream) {
  const float* nodes = (const float*)d_in[0];
  const int* eidx    = (const int*)d_in[1];
  const int* bptr    = (const int*)d_in[2];
  const float* Wq1 = (const float*)d_in[3];
  const float* Wk1 = (const float*)d_in[4];
  const float* Wv1 = (const float*)d_in[5];
  const float* Wr1 = (const float*)d_in[6];
  const float* g1  = (const float*)d_in[7];
  const float* b1  = (const float*)d_in[8];
  const float* Wq2 = (const float*)d_in[9];
  const float* Wk2 = (const float*)d_in[10];
  const float* Wv2 = (const float*)d_in[11];
  const float* g2  = (const float*)d_in[12];
  const float* b2  = (const float*)d_in[13];

  const int N = in_sizes[0] / 13;
  const int E = in_sizes[1] / 2;
  const int B = in_sizes[2] - 1;
  const int* srcA = eidx;
  const int* dstA = eidx + E;

  char* w = (char*)d_ws;
  int* counts    = (int*)w; w += (size_t)N * 4;          // reused as scatter cursor
  int* offsets   = (int*)w; w += (size_t)(N + 1) * 4;
  int* blockSums = (int*)w; w += 256 * 4;
  int* csr_src   = (int*)w; w += (size_t)E * 4;
  w = (char*)(((uintptr_t)w + 255) & ~(uintptr_t)255);
  float2* kvb = (float2*)w; w += (size_t)N * 64 * 8;  // interleaved {k,v}
  float*  H1  = (float*)w;  w += (size_t)N * 64 * 4;

  float* H2 = (float*)d_out;
  float* Q  = H2 + (size_t)N * 64;

  const int NB = (N + 255) / 256;
  const int EB = (E + 255) / 256;
  const int GB = (N + 7) / 8;

  hipMemsetAsync(counts, 0, (size_t)N * 4, stream);
  k_count<<<EB, 256, 0, stream>>>(dstA, E, counts);
  k_scan1<<<NB, 256, 0, stream>>>(counts, N, offsets, blockSums);
  k_scan2<<<1, 256, 0, stream>>>(blockSums, NB);
  k_scan3<<<NB, 256, 0, stream>>>(offsets, counts, blockSums, N, E);
  k_scatter<<<EB, 256, 0, stream>>>(srcA, dstA, E, counts, csr_src);

  k_proj1<<<(N * 64 + 255) / 256, 256, 0, stream>>>(nodes, Wk1, Wv1, N, kvb);
  k_gat1<<<GB, 512, 0, stream>>>(nodes, Wq1, Wr1, (const float4*)kvb, offsets, csr_src,
                                 g1, b1, N, H1);
  k_proj2<<<2048, 256, 0, stream>>>(H1, Wk2, Wv2, N, kvb);
  k_gat2<<<GB, 512, 0, stream>>>(H1, Wq2, (const float4*)kvb, offsets, csr_src,
                                 g2, b2, N, H2);
  k_pool<<<B, 256, 0, stream>>>(H2, bptr, Q);
}

// Round 4
// 317.480 us; speedup vs baseline: 1.3331x; 1.0655x over previous
//
#include <hip/hip_runtime.h>
#include <hip/hip_fp16.h>
#include <math.h>
#include <stdint.h>

#define LN_EPS 1e-5f

// ---- CSR build ----------------------------------------------------------

__global__ void k_count(const int* __restrict__ dstA, int E, int* __restrict__ counts) {
  int e = blockIdx.x * blockDim.x + threadIdx.x;
  if (e < E) atomicAdd(&counts[dstA[e]], 1);
}

__global__ void k_scan1(const int* __restrict__ counts, int N,
                        int* __restrict__ offsets, int* __restrict__ blockSums) {
  __shared__ int sh[256];
  int t = threadIdx.x;
  int i = blockIdx.x * 256 + t;
  int v = (i < N) ? counts[i] : 0;
  sh[t] = v;
  __syncthreads();
  for (int off = 1; off < 256; off <<= 1) {
    int x = (t >= off) ? sh[t - off] : 0;
    __syncthreads();
    sh[t] += x;
    __syncthreads();
  }
  if (i < N) offsets[i] = sh[t] - v;  // exclusive
  if (t == 255) blockSums[blockIdx.x] = sh[t];
}

__global__ void k_scan2(int* __restrict__ blockSums, int NB) {
  __shared__ int sh[256];
  int t = threadIdx.x;
  int v = (t < NB) ? blockSums[t] : 0;
  sh[t] = v;
  __syncthreads();
  for (int off = 1; off < 256; off <<= 1) {
    int x = (t >= off) ? sh[t - off] : 0;
    __syncthreads();
    sh[t] += x;
    __syncthreads();
  }
  if (t < NB) blockSums[t] = sh[t] - v;  // exclusive
}

__global__ void k_scan3(int* __restrict__ offsets, int* __restrict__ cursor,
                        const int* __restrict__ blockSums, int N, int E) {
  int i = blockIdx.x * 256 + threadIdx.x;
  if (i < N) {
    int o = offsets[i] + blockSums[blockIdx.x];
    offsets[i] = o;
    cursor[i] = o;
  }
  if (i == 0) offsets[N] = E;
}

__global__ void k_scatter(const int* __restrict__ srcA, const int* __restrict__ dstA, int E,
                          int* __restrict__ cursor, int* __restrict__ csr_src) {
  int e = blockIdx.x * blockDim.x + threadIdx.x;
  if (e < E) {
    int pos = atomicAdd(&cursor[dstA[e]], 1);
    csr_src[pos] = srcA[e];
  }
}

// ---- Projections: write interleaved fp16 {k,v} per channel --------------

__global__ void k_proj1(const float* __restrict__ x, const float* __restrict__ Wk,
                        const float* __restrict__ Wv, int N,
                        __half2* __restrict__ kvh) {
  int t = blockIdx.x * blockDim.x + threadIdx.x;
  int n = t >> 6, j = t & 63;
  if (n >= N) return;
  const float* xr = x + (size_t)n * 13;
  float ak = 0.f, av = 0.f;
#pragma unroll
  for (int i = 0; i < 13; ++i) {
    float xv = xr[i];
    ak = fmaf(xv, Wk[i * 64 + j], ak);
    av = fmaf(xv, Wv[i * 64 + j], av);
  }
  kvh[t] = __floats2half2_rn(ak, av);
}

// grid-strided: stage W once per block
__global__ void __launch_bounds__(256) k_proj2(
    const float* __restrict__ H1, const float* __restrict__ Wk, const float* __restrict__ Wv,
    int N, __half2* __restrict__ kvh) {
  __shared__ float sWk[64 * 64];
  __shared__ float sWv[64 * 64];
  for (int i = threadIdx.x; i < 64 * 64; i += 256) { sWk[i] = Wk[i]; sWv[i] = Wv[i]; }
  __syncthreads();
  int total = N * 64;
  int stride = gridDim.x * 256;
  for (int t = blockIdx.x * 256 + threadIdx.x; t < total; t += stride) {
    int n = t >> 6, j = t & 63;
    const float* hr = H1 + (size_t)n * 64;
    float ak = 0.f, av = 0.f;
#pragma unroll 8
    for (int i = 0; i < 64; ++i) {
      float xv = hr[i];
      ak = fmaf(xv, sWk[i * 64 + j], ak);
      av = fmaf(xv, sWv[i * 64 + j], av);
    }
    kvh[t] = __floats2half2_rn(ak, av);
  }
}

// ---- GAT edge loop: 16 lanes/edge, 4 ch/lane (fp16 kv), 16 edges/iter ---

__device__ __forceinline__ void edge_body(uint4 w, bool vf, float4 q4,
                                          float& denom, float4& acc) {
  const __half2* ph = (const __half2*)&w;
  float2 c0 = __half22float2(ph[0]);  // {k,v} ch 4s+0
  float2 c1 = __half22float2(ph[1]);
  float2 c2 = __half22float2(ph[2]);
  float2 c3 = __half22float2(ph[3]);
  float p = q4.x * c0.x + q4.y * c1.x + q4.z * c2.x + q4.w * c3.x;
  p += __shfl_xor(p, 1, 64);
  p += __shfl_xor(p, 2, 64);  // 16-ch head dot (4-lane subgroup)
  float ex = vf ? __expf(p) : 0.f;
  denom += ex;
  acc.x = fmaf(ex, c0.y, acc.x);
  acc.y = fmaf(ex, c1.y, acc.y);
  acc.z = fmaf(ex, c2.y, acc.z);
  acc.w = fmaf(ex, c3.y, acc.w);
}

__device__ __forceinline__ void edge_loop_h(const uint4* __restrict__ kvh4,
                                            const int* __restrict__ csr_src,
                                            int e0, int deg, int lane, float4 q4,
                                            float& denom, float4& acc) {
  int grp = lane >> 4;   // edge slot within quad
  int sub = lane & 15;   // channel chunk within row (16 B each)
  for (int base = 0; base < deg; base += 16) {
    int i0 = base + grp, i1 = base + 4 + grp, i2 = base + 8 + grp, i3 = base + 12 + grp;
    bool v0 = i0 < deg, v1 = i1 < deg, v2 = i2 < deg, v3 = i3 < deg;
    int s0 = v0 ? csr_src[e0 + i0] : 0;
    int s1 = v1 ? csr_src[e0 + i1] : 0;
    int s2 = v2 ? csr_src[e0 + i2] : 0;
    int s3 = v3 ? csr_src[e0 + i3] : 0;
    uint4 w0 = kvh4[(size_t)s0 * 16 + sub];
    uint4 w1 = kvh4[(size_t)s1 * 16 + sub];
    uint4 w2 = kvh4[(size_t)s2 * 16 + sub];
    uint4 w3 = kvh4[(size_t)s3 * 16 + sub];
    edge_body(w0, v0, q4, denom, acc);
    edge_body(w1, v1, q4, denom, acc);
    edge_body(w2, v2, q4, denom, acc);
    edge_body(w3, v3, q4, denom, acc);
  }
  // combine the 4 edge-slots (lanes l, l+16, l+32, l+48 hold same channels)
#pragma unroll
  for (int off = 16; off <= 32; off <<= 1) {
    acc.x += __shfl_xor(acc.x, off, 64);
    acc.y += __shfl_xor(acc.y, off, 64);
    acc.z += __shfl_xor(acc.z, off, 64);
    acc.w += __shfl_xor(acc.w, off, 64);
    denom += __shfl_xor(denom, off, 64);
  }
}

__device__ __forceinline__ void ln_store(float4 out4, float4 r4, int lane,
                                         const float* __restrict__ g,
                                         const float* __restrict__ b,
                                         float* __restrict__ dst) {
  float4 h;
  h.x = out4.x + r4.x; h.y = out4.y + r4.y; h.z = out4.z + r4.z; h.w = out4.w + r4.w;
  float s = (h.x + h.y) + (h.z + h.w);
#pragma unroll
  for (int off = 1; off <= 8; off <<= 1) s += __shfl_xor(s, off, 64);
  float mu = s * 0.015625f;
  float4 d;
  d.x = h.x - mu; d.y = h.y - mu; d.z = h.z - mu; d.w = h.w - mu;
  float v = (d.x * d.x + d.y * d.y) + (d.z * d.z + d.w * d.w);
#pragma unroll
  for (int off = 1; off <= 8; off <<= 1) v += __shfl_xor(v, off, 64);
  float rs = rsqrtf(v * 0.015625f + LN_EPS);
  if (lane < 16) {
    int c = lane * 4;
    float4 g4 = *(const float4*)&g[c];
    float4 b4 = *(const float4*)&b[c];
    float4 o;
    o.x = fmaf(g4.x, d.x * rs, b4.x);
    o.y = fmaf(g4.y, d.y * rs, b4.y);
    o.z = fmaf(g4.z, d.z * rs, b4.z);
    o.w = fmaf(g4.w, d.w * rs, b4.w);
    *(float4*)&dst[c] = o;
  }
}

// ---- Layer 1: one wave per node -----------------------------------------

__global__ void __launch_bounds__(512) k_gat1(
    const float* __restrict__ x, const float* __restrict__ Wq, const float* __restrict__ Wr,
    const uint4* __restrict__ kvh4,
    const int* __restrict__ offsets, const int* __restrict__ csr_src,
    const float* __restrict__ g, const float* __restrict__ b,
    int N, float* __restrict__ H1) {
  __shared__ float sWq[13 * 64];
  __shared__ float sWr[13 * 64];
  for (int i = threadIdx.x; i < 13 * 64; i += 512) { sWq[i] = Wq[i]; sWr[i] = Wr[i]; }
  __syncthreads();
  int wid = threadIdx.x >> 6, lane = threadIdx.x & 63;
  int n = blockIdx.x * 8 + wid;
  if (n >= N) return;
  const float* xr = x + (size_t)n * 13;
  float q = 0.f, r = 0.f;
#pragma unroll
  for (int i = 0; i < 13; ++i) {
    float xv = xr[i];
    q = fmaf(xv, sWq[i * 64 + lane], q);
    r = fmaf(xv, sWr[i * 64 + lane], r);
  }
  q *= 0.25f;  // 1/sqrt(dh)
  int bl = (lane & 15) * 4;
  float4 q4, r4;
  q4.x = __shfl(q, bl + 0, 64); q4.y = __shfl(q, bl + 1, 64);
  q4.z = __shfl(q, bl + 2, 64); q4.w = __shfl(q, bl + 3, 64);
  r4.x = __shfl(r, bl + 0, 64); r4.y = __shfl(r, bl + 1, 64);
  r4.z = __shfl(r, bl + 2, 64); r4.w = __shfl(r, bl + 3, 64);
  int e0 = offsets[n];
  int deg = offsets[n + 1] - e0;
  float denom = 0.f;
  float4 acc = make_float4(0.f, 0.f, 0.f, 0.f);
  edge_loop_h(kvh4, csr_src, e0, deg, lane, q4, denom, acc);
  float inv = 1.0f / (denom + 1e-16f);
  float4 out4 = make_float4(acc.x * inv, acc.y * inv, acc.z * inv, acc.w * inv);
  ln_store(out4, r4, lane, g, b, H1 + (size_t)n * 64);
}

// ---- Layer 2 ------------------------------------------------------------

__global__ void __launch_bounds__(512) k_gat2(
    const float* __restrict__ H1, const float* __restrict__ Wq,
    const uint4* __restrict__ kvh4,
    const int* __restrict__ offsets, const int* __restrict__ csr_src,
    const float* __restrict__ g, const float* __restrict__ b,
    int N, float* __restrict__ H2) {
  __shared__ float sWq[64 * 64];
  for (int i = threadIdx.x; i < 64 * 64; i += 512) sWq[i] = Wq[i];
  __syncthreads();
  int wid = threadIdx.x >> 6, lane = threadIdx.x & 63;
  int n = blockIdx.x * 8 + wid;
  if (n >= N) return;
  const float* hr = H1 + (size_t)n * 64;
  float q = 0.f;
#pragma unroll 8
  for (int i = 0; i < 64; ++i) q = fmaf(hr[i], sWq[i * 64 + lane], q);
  q *= 0.25f;
  int bl = (lane & 15) * 4;
  float4 q4;
  q4.x = __shfl(q, bl + 0, 64); q4.y = __shfl(q, bl + 1, 64);
  q4.z = __shfl(q, bl + 2, 64); q4.w = __shfl(q, bl + 3, 64);
  float4 r4 = *(const float4*)&hr[bl];  // identity residual
  int e0 = offsets[n];
  int deg = offsets[n + 1] - e0;
  float denom = 0.f;
  float4 acc = make_float4(0.f, 0.f, 0.f, 0.f);
  edge_loop_h(kvh4, csr_src, e0, deg, lane, q4, denom, acc);
  float inv = 1.0f / (denom + 1e-16f);
  float4 out4 = make_float4(acc.x * inv, acc.y * inv, acc.z * inv, acc.w * inv);
  ln_store(out4, r4, lane, g, b, H2 + (size_t)n * 64);
}

// ---- Pooling ------------------------------------------------------------

__global__ void k_pool(const float* __restrict__ H2, const int* __restrict__ ptr,
                       float* __restrict__ Q) {
  __shared__ float sh[4 * 64];
  int gI = blockIdx.x;
  int start = ptr[gI], end = ptr[gI + 1];
  int wid = threadIdx.x >> 6, lane = threadIdx.x & 63;
  float acc = 0.f;
  for (int n = start + wid; n < end; n += 4) acc += H2[(size_t)n * 64 + lane];
  sh[wid * 64 + lane] = acc;
  __syncthreads();
  if (wid == 0) {
    float s = sh[lane] + sh[64 + lane] + sh[128 + lane] + sh[192 + lane];
    Q[gI * 64 + lane] = s / (float)(end - start);
  }
}

// ---- Launch -------------------------------------------------------------

extern "C" void kernel_launch(void* const* d_in, const int* in_sizes, int n_in,
                              void* d_out, int out_size, void* d_ws, size_t ws_size,
                              hipStream_t stream) {
  const float* nodes = (const float*)d_in[0];
  const int* eidx    = (const int*)d_in[1];
  const int* bptr    = (const int*)d_in[2];
  const float* Wq1 = (const float*)d_in[3];
  const float* Wk1 = (const float*)d_in[4];
  const float* Wv1 = (const float*)d_in[5];
  const float* Wr1 = (const float*)d_in[6];
  const float* g1  = (const float*)d_in[7];
  const float* b1  = (const float*)d_in[8];
  const float* Wq2 = (const float*)d_in[9];
  const float* Wk2 = (const float*)d_in[10];
  const float* Wv2 = (const float*)d_in[11];
  const float* g2  = (const float*)d_in[12];
  const float* b2  = (const float*)d_in[13];

  const int N = in_sizes[0] / 13;
  const int E = in_sizes[1] / 2;
  const int B = in_sizes[2] - 1;
  const int* srcA = eidx;
  const int* dstA = eidx + E;

  char* w = (char*)d_ws;
  int* counts    = (int*)w; w += (size_t)N * 4;          // reused as scatter cursor
  int* offsets   = (int*)w; w += (size_t)(N + 1) * 4;
  int* blockSums = (int*)w; w += 256 * 4;
  int* csr_src   = (int*)w; w += (size_t)E * 4;
  w = (char*)(((uintptr_t)w + 255) & ~(uintptr_t)255);
  __half2* kvh = (__half2*)w; w += (size_t)N * 64 * 4;  // fp16 interleaved {k,v}
  float*   H1  = (float*)w;   w += (size_t)N * 64 * 4;

  float* H2 = (float*)d_out;
  float* Q  = H2 + (size_t)N * 64;

  const int NB = (N + 255) / 256;
  const int EB = (E + 255) / 256;
  const int GB = (N + 7) / 8;

  hipMemsetAsync(counts, 0, (size_t)N * 4, stream);
  k_count<<<EB, 256, 0, stream>>>(dstA, E, counts);
  k_scan1<<<NB, 256, 0, stream>>>(counts, N, offsets, blockSums);
  k_scan2<<<1, 256, 0, stream>>>(blockSums, NB);
  k_scan3<<<NB, 256, 0, stream>>>(offsets, counts, blockSums, N, E);
  k_scatter<<<EB, 256, 0, stream>>>(srcA, dstA, E, counts, csr_src);

  k_proj1<<<(N * 64 + 255) / 256, 256, 0, stream>>>(nodes, Wk1, Wv1, N, kvh);
  k_gat1<<<GB, 512, 0, stream>>>(nodes, Wq1, Wr1, (const uint4*)kvh, offsets, csr_src,
                                 g1, b1, N, H1);
  k_proj2<<<2048, 256, 0, stream>>>(H1, Wk2, Wv2, N, kvh);
  k_gat2<<<GB, 512, 0, stream>>>(H1, Wq2, (const uint4*)kvh, offsets, csr_src,
                                 g2, b2, N, H2);
  k_pool<<<B, 256, 0, stream>>>(H2, bptr, Q);
}

// Round 5
// 304.799 us; speedup vs baseline: 1.3885x; 1.0416x over previous
//
#include <hip/hip_runtime.h>
#include <hip/hip_fp16.h>
#include <math.h>
#include <stdint.h>

#define LN_EPS 1e-5f

// ---- CSR build ----------------------------------------------------------

__global__ void k_count(const int* __restrict__ dstA, int E, int* __restrict__ counts) {
  int e = blockIdx.x * blockDim.x + threadIdx.x;
  if (e < E) atomicAdd(&counts[dstA[e]], 1);
}

__global__ void k_scan1(const int* __restrict__ counts, int N,
                        int* __restrict__ offsets, int* __restrict__ blockSums) {
  __shared__ int sh[256];
  int t = threadIdx.x;
  int i = blockIdx.x * 256 + t;
  int v = (i < N) ? counts[i] : 0;
  sh[t] = v;
  __syncthreads();
  for (int off = 1; off < 256; off <<= 1) {
    int x = (t >= off) ? sh[t - off] : 0;
    __syncthreads();
    sh[t] += x;
    __syncthreads();
  }
  if (i < N) offsets[i] = sh[t] - v;  // exclusive within block
  if (t == 255) blockSums[blockIdx.x] = sh[t];
}

// adds prefix of blockSums (computed locally) and fills cursor; no scan2 kernel
__global__ void k_scan3(int* __restrict__ offsets, int* __restrict__ cursor,
                        const int* __restrict__ blockSums, int N, int E, int NB) {
  __shared__ int sh[256];
  int t = threadIdx.x;
  int bid = blockIdx.x;
  int v = (t < NB && t < bid) ? blockSums[t] : 0;  // sum of previous blocks
  sh[t] = v;
  __syncthreads();
  for (int off = 128; off >= 1; off >>= 1) {
    if (t < off) sh[t] += sh[t + off];
    __syncthreads();
  }
  int prefix = sh[0];
  int i = bid * 256 + t;
  if (i < N) {
    int o = offsets[i] + prefix;
    offsets[i] = o;
    cursor[i] = o;
  }
  if (i == 0) offsets[N] = E;
}

__global__ void k_scatter(const int* __restrict__ srcA, const int* __restrict__ dstA, int E,
                          int* __restrict__ cursor, int* __restrict__ csr_src) {
  int e = blockIdx.x * blockDim.x + threadIdx.x;
  if (e < E) {
    int pos = atomicAdd(&cursor[dstA[e]], 1);
    csr_src[pos] = srcA[e];
  }
}

// ---- Projections --------------------------------------------------------
// Layer 1: kv (fp16 interleaved {k,v}), q (fp16, pre-scaled 1/4), r (fp32)

__global__ void k_proj1(const float* __restrict__ x, const float* __restrict__ Wk,
                        const float* __restrict__ Wv, const float* __restrict__ Wq,
                        const float* __restrict__ Wr, int N,
                        __half2* __restrict__ kvh, __half* __restrict__ qh,
                        float* __restrict__ rb) {
  int t = blockIdx.x * blockDim.x + threadIdx.x;
  int n = t >> 6, j = t & 63;
  if (n >= N) return;
  const float* xr = x + (size_t)n * 13;
  float ak = 0.f, av = 0.f, aq = 0.f, ar = 0.f;
#pragma unroll
  for (int i = 0; i < 13; ++i) {
    float xv = xr[i];
    ak = fmaf(xv, Wk[i * 64 + j], ak);
    av = fmaf(xv, Wv[i * 64 + j], av);
    aq = fmaf(xv, Wq[i * 64 + j], aq);
    ar = fmaf(xv, Wr[i * 64 + j], ar);
  }
  kvh[t] = __floats2half2_rn(ak, av);
  qh[t] = __float2half(aq * 0.25f);
  rb[t] = ar;
}

// Layer 2 (grid-strided): kv fp16 + q fp16 from H1
__global__ void __launch_bounds__(256) k_proj2(
    const float* __restrict__ H1, const float* __restrict__ Wk, const float* __restrict__ Wv,
    const float* __restrict__ Wq, int N, __half2* __restrict__ kvh,
    __half* __restrict__ qh) {
  __shared__ float sWk[64 * 64];
  __shared__ float sWv[64 * 64];
  __shared__ float sWq[64 * 64];
  for (int i = threadIdx.x; i < 64 * 64; i += 256) {
    sWk[i] = Wk[i]; sWv[i] = Wv[i]; sWq[i] = Wq[i];
  }
  __syncthreads();
  int total = N * 64;
  int stride = gridDim.x * 256;
  for (int t = blockIdx.x * 256 + threadIdx.x; t < total; t += stride) {
    int n = t >> 6, j = t & 63;
    const float* hr = H1 + (size_t)n * 64;
    float ak = 0.f, av = 0.f, aq = 0.f;
#pragma unroll 8
    for (int i = 0; i < 64; ++i) {
      float xv = hr[i];
      ak = fmaf(xv, sWk[i * 64 + j], ak);
      av = fmaf(xv, sWv[i * 64 + j], av);
      aq = fmaf(xv, sWq[i * 64 + j], aq);
    }
    kvh[t] = __floats2half2_rn(ak, av);
    qh[t] = __float2half(aq * 0.25f);
  }
}

// ---- GAT edge loop: 16 lanes/edge, 4 ch/lane (fp16 kv), 16 edges/iter ---

__device__ __forceinline__ void edge_body(uint4 w, bool vf, float4 q4,
                                          float& denom, float4& acc) {
  const __half2* ph = (const __half2*)&w;
  float2 c0 = __half22float2(ph[0]);  // {k,v} ch 4s+0
  float2 c1 = __half22float2(ph[1]);
  float2 c2 = __half22float2(ph[2]);
  float2 c3 = __half22float2(ph[3]);
  float p = q4.x * c0.x + q4.y * c1.x + q4.z * c2.x + q4.w * c3.x;
  p += __shfl_xor(p, 1, 64);
  p += __shfl_xor(p, 2, 64);  // 16-ch head dot (4-lane subgroup)
  float ex = vf ? __expf(p) : 0.f;
  denom += ex;
  acc.x = fmaf(ex, c0.y, acc.x);
  acc.y = fmaf(ex, c1.y, acc.y);
  acc.z = fmaf(ex, c2.y, acc.z);
  acc.w = fmaf(ex, c3.y, acc.w);
}

__device__ __forceinline__ void edge_loop_h(const uint4* __restrict__ kvh4,
                                            const int* __restrict__ csr_src,
                                            int e0, int deg, int lane, float4 q4,
                                            float& denom, float4& acc) {
  int grp = lane >> 4;   // edge slot within quad
  int sub = lane & 15;   // 16B channel chunk within row
  for (int base = 0; base < deg; base += 16) {
    int i0 = base + grp, i1 = base + 4 + grp, i2 = base + 8 + grp, i3 = base + 12 + grp;
    bool v0 = i0 < deg, v1 = i1 < deg, v2 = i2 < deg, v3 = i3 < deg;
    int s0 = v0 ? csr_src[e0 + i0] : 0;
    int s1 = v1 ? csr_src[e0 + i1] : 0;
    int s2 = v2 ? csr_src[e0 + i2] : 0;
    int s3 = v3 ? csr_src[e0 + i3] : 0;
    uint4 w0 = kvh4[(size_t)s0 * 16 + sub];
    uint4 w1 = kvh4[(size_t)s1 * 16 + sub];
    uint4 w2 = kvh4[(size_t)s2 * 16 + sub];
    uint4 w3 = kvh4[(size_t)s3 * 16 + sub];
    edge_body(w0, v0, q4, denom, acc);
    edge_body(w1, v1, q4, denom, acc);
    edge_body(w2, v2, q4, denom, acc);
    edge_body(w3, v3, q4, denom, acc);
  }
  // combine the 4 edge-slots (lanes l, l+16, l+32, l+48 hold same channels)
#pragma unroll
  for (int off = 16; off <= 32; off <<= 1) {
    acc.x += __shfl_xor(acc.x, off, 64);
    acc.y += __shfl_xor(acc.y, off, 64);
    acc.z += __shfl_xor(acc.z, off, 64);
    acc.w += __shfl_xor(acc.w, off, 64);
    denom += __shfl_xor(denom, off, 64);
  }
}

__device__ __forceinline__ void ln_store(float4 out4, float4 r4, int lane,
                                         const float* __restrict__ g,
                                         const float* __restrict__ b,
                                         float* __restrict__ dst) {
  float4 h;
  h.x = out4.x + r4.x; h.y = out4.y + r4.y; h.z = out4.z + r4.z; h.w = out4.w + r4.w;
  float s = (h.x + h.y) + (h.z + h.w);
#pragma unroll
  for (int off = 1; off <= 8; off <<= 1) s += __shfl_xor(s, off, 64);
  float mu = s * 0.015625f;
  float4 d;
  d.x = h.x - mu; d.y = h.y - mu; d.z = h.z - mu; d.w = h.w - mu;
  float v = (d.x * d.x + d.y * d.y) + (d.z * d.z + d.w * d.w);
#pragma unroll
  for (int off = 1; off <= 8; off <<= 1) v += __shfl_xor(v, off, 64);
  float rs = rsqrtf(v * 0.015625f + LN_EPS);
  if (lane < 16) {
    int c = lane * 4;
    float4 g4 = *(const float4*)&g[c];
    float4 b4 = *(const float4*)&b[c];
    float4 o;
    o.x = fmaf(g4.x, d.x * rs, b4.x);
    o.y = fmaf(g4.y, d.y * rs, b4.y);
    o.z = fmaf(g4.z, d.z * rs, b4.z);
    o.w = fmaf(g4.w, d.w * rs, b4.w);
    *(float4*)&dst[c] = o;
  }
}

// ---- GAT layers: one wave per node, no LDS, no syncthreads --------------

__global__ void __launch_bounds__(256) k_gat1(
    const __half* __restrict__ qh, const float* __restrict__ rb,
    const uint4* __restrict__ kvh4,
    const int* __restrict__ offsets, const int* __restrict__ csr_src,
    const float* __restrict__ g, const float* __restrict__ b,
    int N, float* __restrict__ H1) {
  int wid = threadIdx.x >> 6, lane = threadIdx.x & 63;
  int n = blockIdx.x * 4 + wid;
  if (n >= N) return;
  int sub = lane & 15;
  // q: 4 fp16 ch, pre-scaled; r: 4 fp32 ch
  uint2 qw = *(const uint2*)&qh[(size_t)n * 64 + sub * 4];
  const __half2* qp = (const __half2*)&qw;
  float2 qa = __half22float2(qp[0]), qb = __half22float2(qp[1]);
  float4 q4 = make_float4(qa.x, qa.y, qb.x, qb.y);
  float4 r4 = *(const float4*)&rb[(size_t)n * 64 + sub * 4];
  int e0 = offsets[n];
  int deg = offsets[n + 1] - e0;
  float denom = 0.f;
  float4 acc = make_float4(0.f, 0.f, 0.f, 0.f);
  edge_loop_h(kvh4, csr_src, e0, deg, lane, q4, denom, acc);
  float inv = 1.0f / (denom + 1e-16f);
  float4 out4 = make_float4(acc.x * inv, acc.y * inv, acc.z * inv, acc.w * inv);
  ln_store(out4, r4, lane, g, b, H1 + (size_t)n * 64);
}

__global__ void __launch_bounds__(256) k_gat2(
    const float* __restrict__ H1, const __half* __restrict__ qh,
    const uint4* __restrict__ kvh4,
    const int* __restrict__ offsets, const int* __restrict__ csr_src,
    const float* __restrict__ g, const float* __restrict__ b,
    int N, float* __restrict__ H2) {
  int wid = threadIdx.x >> 6, lane = threadIdx.x & 63;
  int n = blockIdx.x * 4 + wid;
  if (n >= N) return;
  int sub = lane & 15;
  uint2 qw = *(const uint2*)&qh[(size_t)n * 64 + sub * 4];
  const __half2* qp = (const __half2*)&qw;
  float2 qa = __half22float2(qp[0]), qb = __half22float2(qp[1]);
  float4 q4 = make_float4(qa.x, qa.y, qb.x, qb.y);
  float4 r4 = *(const float4*)&H1[(size_t)n * 64 + sub * 4];  // identity residual
  int e0 = offsets[n];
  int deg = offsets[n + 1] - e0;
  float denom = 0.f;
  float4 acc = make_float4(0.f, 0.f, 0.f, 0.f);
  edge_loop_h(kvh4, csr_src, e0, deg, lane, q4, denom, acc);
  float inv = 1.0f / (denom + 1e-16f);
  float4 out4 = make_float4(acc.x * inv, acc.y * inv, acc.z * inv, acc.w * inv);
  ln_store(out4, r4, lane, g, b, H2 + (size_t)n * 64);
}

// ---- Pooling ------------------------------------------------------------

__global__ void k_pool(const float* __restrict__ H2, const int* __restrict__ ptr,
                       float* __restrict__ Q) {
  __shared__ float sh[4 * 64];
  int gI = blockIdx.x;
  int start = ptr[gI], end = ptr[gI + 1];
  int wid = threadIdx.x >> 6, lane = threadIdx.x & 63;
  float acc = 0.f;
  for (int n = start + wid; n < end; n += 4) acc += H2[(size_t)n * 64 + lane];
  sh[wid * 64 + lane] = acc;
  __syncthreads();
  if (wid == 0) {
    float s = sh[lane] + sh[64 + lane] + sh[128 + lane] + sh[192 + lane];
    Q[gI * 64 + lane] = s / (float)(end - start);
  }
}

// ---- Launch -------------------------------------------------------------

extern "C" void kernel_launch(void* const* d_in, const int* in_sizes, int n_in,
                              void* d_out, int out_size, void* d_ws, size_t ws_size,
                              hipStream_t stream) {
  const float* nodes = (const float*)d_in[0];
  const int* eidx    = (const int*)d_in[1];
  const int* bptr    = (const int*)d_in[2];
  const float* Wq1 = (const float*)d_in[3];
  const float* Wk1 = (const float*)d_in[4];
  const float* Wv1 = (const float*)d_in[5];
  const float* Wr1 = (const float*)d_in[6];
  const float* g1  = (const float*)d_in[7];
  const float* b1  = (const float*)d_in[8];
  const float* Wq2 = (const float*)d_in[9];
  const float* Wk2 = (const float*)d_in[10];
  const float* Wv2 = (const float*)d_in[11];
  const float* g2  = (const float*)d_in[12];
  const float* b2  = (const float*)d_in[13];

  const int N = in_sizes[0] / 13;
  const int E = in_sizes[1] / 2;
  const int B = in_sizes[2] - 1;
  const int* srcA = eidx;
  const int* dstA = eidx + E;

  char* w = (char*)d_ws;
  int* counts    = (int*)w; w += (size_t)N * 4;          // reused as scatter cursor
  int* offsets   = (int*)w; w += (size_t)(N + 1) * 4;
  int* blockSums = (int*)w; w += 256 * 4;
  int* csr_src   = (int*)w; w += (size_t)E * 4;
  w = (char*)(((uintptr_t)w + 255) & ~(uintptr_t)255);
  __half2* kvh = (__half2*)w; w += (size_t)N * 64 * 4;  // fp16 interleaved {k,v}
  __half*  qh  = (__half*)w;  w += (size_t)N * 64 * 2;  // fp16 q, pre-scaled (both layers)
  float*   rb  = (float*)w;   w += (size_t)N * 64 * 4;  // fp32 residual (layer 1)
  float*   H1  = (float*)w;   w += (size_t)N * 64 * 4;

  float* H2 = (float*)d_out;
  float* Q  = H2 + (size_t)N * 64;

  const int NB = (N + 255) / 256;
  const int EB = (E + 255) / 256;
  const int GB = (N + 3) / 4;

  hipMemsetAsync(counts, 0, (size_t)N * 4, stream);
  k_count<<<EB, 256, 0, stream>>>(dstA, E, counts);
  k_scan1<<<NB, 256, 0, stream>>>(counts, N, offsets, blockSums);
  k_scan3<<<NB, 256, 0, stream>>>(offsets, counts, blockSums, N, E, NB);
  k_scatter<<<EB, 256, 0, stream>>>(srcA, dstA, E, counts, csr_src);

  k_proj1<<<(N * 64 + 255) / 256, 256, 0, stream>>>(nodes, Wk1, Wv1, Wq1, Wr1, N,
                                                    kvh, qh, rb);
  k_gat1<<<GB, 256, 0, stream>>>(qh, rb, (const uint4*)kvh, offsets, csr_src,
                                 g1, b1, N, H1);
  k_proj2<<<2048, 256, 0, stream>>>(H1, Wk2, Wv2, Wq2, N, kvh, qh);
  k_gat2<<<GB, 256, 0, stream>>>(H1, qh, (const uint4*)kvh, offsets, csr_src,
                                 g2, b2, N, H2);
  k_pool<<<B, 256, 0, stream>>>(H2, bptr, Q);
}